// Round 10
// baseline (224.402 us; speedup 1.0000x reference)
//
#include <hip/hip_runtime.h>
#include <stdint.h>

typedef __attribute__((ext_vector_type(8))) __bf16 bf16x8;
typedef __attribute__((ext_vector_type(4))) __bf16 bf16x4;
typedef __attribute__((ext_vector_type(4))) float  f32x4;

#define DEV __device__ __forceinline__

DEV void gload16(const void* g, void* l) {
  __builtin_amdgcn_global_load_lds((const __attribute__((address_space(1))) uint32_t*)g,
                                   (__attribute__((address_space(3))) uint32_t*)l,
                                   16, 0, 0);
}

DEV f32x4 mfma16(bf16x8 a, bf16x8 b, f32x4 c) {
  return __builtin_amdgcn_mfma_f32_16x16x32_bf16(a, b, c, 0, 0, 0);
}

// ---------------- workspace layout (bytes) ----------------
#define XB_OFF   0UL            // 16384 x 1088 bf16 = 35,651,584 ; reused as S (32MB) after k_gemm
#define S_OFF    0UL            // S: 4 batches x 2048 x 2048 bf16 = 33,554,432 (< XB region)
#define Q_OFF    35651584UL     // 16384 x 512 bf16  = 16,777,216
#define K_OFF    52428800UL
#define V_OFF    69206016UL
#define VT_OFF   85983232UL     // [8][512][2048] bf16
#define WT_OFF   102760448UL    // 1536 x 1088 bf16 = 3,342,336
#define BIAS_OFF 106102784UL    // 1536 f32
#define GATE_OFF 106108928UL    // 16384 f32

// ============ kernel 1: xb (concat, bf16) + gate ============
__global__ __launch_bounds__(256) void k_xbgate(
    const float* __restrict__ tf, const float* __restrict__ env,
    const float* __restrict__ Wg, const float* __restrict__ bg,
    __bf16* __restrict__ xb, float* __restrict__ gate) {
  const int row = blockIdx.x;     // 0..16383
  const int t   = threadIdx.x;    // 0..255
  const int b   = row >> 11;
  const float4 v  = ((const float4*)(tf + (size_t)row * 1024))[t];
  const float4 wv = ((const float4*)Wg)[t];
  float dot = v.x * wv.x + v.y * wv.y + v.z * wv.z + v.w * wv.w;
  bf16x4 o; o.x = (__bf16)v.x; o.y = (__bf16)v.y; o.z = (__bf16)v.z; o.w = (__bf16)v.w;
  *(bf16x4*)(xb + (size_t)row * 1088 + t * 4) = o;
  if (t < 16) {
    const float4 e  = ((const float4*)(env + b * 64))[t];
    const float4 we = ((const float4*)Wg)[256 + t];
    dot += e.x * we.x + e.y * we.y + e.z * we.z + e.w * we.w;
    bf16x4 oe; oe.x = (__bf16)e.x; oe.y = (__bf16)e.y; oe.z = (__bf16)e.z; oe.w = (__bf16)e.w;
    *(bf16x4*)(xb + (size_t)row * 1088 + 1024 + t * 4) = oe;
  }
  #pragma unroll
  for (int m = 1; m < 64; m <<= 1) dot += __shfl_xor(dot, m, 64);
  __shared__ float red[4];
  if ((t & 63) == 0) red[t >> 6] = dot;
  __syncthreads();
  if (t == 0) {
    const float d = red[0] + red[1] + red[2] + red[3] + bg[0];
    gate[row] = 0.03125f / (1.0f + __expf(-d));   // sigmoid * 1/sqrt(1024)
  }
}

// ============ kernel 2: Wt[n][k] = W[k][n] (bf16) + bias ============
__global__ __launch_bounds__(256) void k_wt(
    const float* __restrict__ Wq, const float* __restrict__ Wk, const float* __restrict__ Wv,
    const float* __restrict__ bq, const float* __restrict__ bk, const float* __restrict__ bv,
    __bf16* __restrict__ Wt, float* __restrict__ biasc) {
  const int n = blockIdx.x;      // 0..1535
  const int t = threadIdx.x;
  const float* W; const float* bias; int col;
  if (n < 512)       { W = Wq; bias = bq; col = n; }
  else if (n < 1024) { W = Wk; bias = bk; col = n - 512; }
  else               { W = Wv; bias = bv; col = n - 1024; }
  for (int kk = t; kk < 1088; kk += 256)
    Wt[(size_t)n * 1088 + kk] = (__bf16)W[(size_t)kk * 512 + col];
  if (t == 0) biasc[n] = bias[col];
}

// ============ kernel 3: QKV GEMM  M=16384 N=1536 K=1088 ============
__global__ __launch_bounds__(256, 2) void k_gemm(
    const __bf16* __restrict__ xb, const __bf16* __restrict__ Wt,
    const float* __restrict__ biasc, const float* __restrict__ gate,
    __bf16* __restrict__ q, __bf16* __restrict__ k, __bf16* __restrict__ v) {
  __shared__ alignas(16) __bf16 As[8192];
  __shared__ alignas(16) __bf16 Bs[8192];
  const int id = blockIdx.x;
  const int xcd = id & 7, local = id >> 3;
  const int bm = xcd * 16 + (local & 15);
  const int bn = local >> 4;
  const int tid = threadIdx.x, w = tid >> 6, lane = tid & 63;
  const int g = lane >> 4, l15 = lane & 15;
  const int wm = w >> 1, wn = w & 1;
  f32x4 acc[4][4] = {};
  const char* Ab = (const char*)(xb + (size_t)bm * 128 * 1088);
  const char* Bb = (const char*)(Wt + (size_t)bn * 128 * 1088);

  for (int kt = 0; kt < 17; ++kt) {
    const int k0b = kt * 128;
    #pragma unroll
    for (int i = 0; i < 4; ++i) {
      const int L = i * 4096 + w * 1024 + lane * 16;
      const int row = L >> 7;
      const int ch = (L >> 4) & 7;
      const int sch = ch ^ (row & 7);
      gload16(Ab + (size_t)row * 2176 + k0b + sch * 16, (char*)As + L);
      gload16(Bb + (size_t)row * 2176 + k0b + sch * 16, (char*)Bs + L);
    }
    __syncthreads();
    #pragma unroll
    for (int kk = 0; kk < 2; ++kk) {
      bf16x8 aF[4], bF[4];
      #pragma unroll
      for (int i = 0; i < 4; ++i) {
        const int rowa = wm * 64 + i * 16 + l15;
        const int cha = (kk * 4 + g) ^ (rowa & 7);
        aF[i] = *(const bf16x8*)((const char*)As + rowa * 128 + cha * 16);
        const int rowb = wn * 64 + i * 16 + l15;
        const int chb = (kk * 4 + g) ^ (rowb & 7);
        bF[i] = *(const bf16x8*)((const char*)Bs + rowb * 128 + chb * 16);
      }
      #pragma unroll
      for (int i = 0; i < 4; ++i)
        #pragma unroll
        for (int j = 0; j < 4; ++j)
          acc[i][j] = mfma16(aF[i], bF[j], acc[i][j]);
    }
    __syncthreads();
  }

  const int which = bn >> 2;
  __bf16* outp = (which == 0) ? q : (which == 1) ? k : v;
  const int ncolbase = bn * 128 + wn * 64 - which * 512;
  #pragma unroll
  for (int i = 0; i < 4; ++i) {
    #pragma unroll
    for (int r = 0; r < 4; ++r) {
      const int mrow = bm * 128 + wm * 64 + i * 16 + g * 4 + r;
      const float gt = (which == 0) ? gate[mrow] : 1.0f;
      #pragma unroll
      for (int j = 0; j < 4; ++j) {
        const int ncol = ncolbase + j * 16 + l15;
        float val = acc[i][j][r] + biasc[which * 512 + ncol];
        if (which == 0) val *= gt;
        outp[(size_t)mrow * 512 + ncol] = (__bf16)val;
      }
    }
  }
}

// ============ kernel 4: v [16384][512] -> vT [8][512][2048] ============
__global__ __launch_bounds__(256) void k_vtr(const __bf16* __restrict__ v,
                                             __bf16* __restrict__ vT) {
  __shared__ __bf16 tile[64][72];
  const int st = blockIdx.x, dt = blockIdx.y, b = blockIdx.z;
  const int t = threadIdx.x;
  {
    const int sl = t >> 2, dl = (t & 3) * 16;
    const __bf16* src = v + ((size_t)(b * 2048 + st * 64 + sl)) * 512 + dt * 64 + dl;
    *(bf16x8*)&tile[sl][dl]     = *(const bf16x8*)src;
    *(bf16x8*)&tile[sl][dl + 8] = *(const bf16x8*)(src + 8);
  }
  __syncthreads();
  {
    const int dl = t >> 2, sl = (t & 3) * 16;
    bf16x8 w0, w1;
    #pragma unroll
    for (int j = 0; j < 8; ++j) { w0[j] = tile[sl + j][dl]; w1[j] = tile[sl + 8 + j][dl]; }
    __bf16* dst = vT + ((size_t)(b * 512 + dt * 64 + dl)) * 2048 + st * 64 + sl;
    *(bf16x8*)dst = w0;
    *(bf16x8*)(dst + 8) = w1;
  }
}

// ============ kernel 5: S = exp(Q @ K^T) for a 4-batch group ============
// M=N=2048 per batch, K=512. 128x128 tile, m97 structure (validated k_gemm).
// grid = 4 batches x 16 mt x 16 nt = 1024. Gate/32 pre-folded into Q; m=0 softmax.
__global__ __launch_bounds__(256, 2) void k_sexp(
    const __bf16* __restrict__ q, const __bf16* __restrict__ kg,
    __bf16* __restrict__ S) {
  __shared__ alignas(16) __bf16 As[8192];
  __shared__ alignas(16) __bf16 Bs[8192];
  const int id = blockIdx.x;
  const int batch = id >> 8, local = id & 255;
  const int mt = local & 15, nt = local >> 4;
  const int tid = threadIdx.x, w = tid >> 6, lane = tid & 63;
  const int g = lane >> 4, l15 = lane & 15;
  const int wm = w >> 1, wn = w & 1;
  f32x4 acc[4][4] = {};
  const char* Ab = (const char*)(q  + ((size_t)batch * 2048 + mt * 128) * 512);
  const char* Bb = (const char*)(kg + ((size_t)batch * 2048 + nt * 128) * 512);

  for (int kt = 0; kt < 8; ++kt) {
    const int k0b = kt * 128;
    #pragma unroll
    for (int i = 0; i < 4; ++i) {
      const int L = i * 4096 + w * 1024 + lane * 16;
      const int row = L >> 7;
      const int ch = (L >> 4) & 7;
      const int sch = ch ^ (row & 7);
      gload16(Ab + (size_t)row * 1024 + k0b + sch * 16, (char*)As + L);
      gload16(Bb + (size_t)row * 1024 + k0b + sch * 16, (char*)Bs + L);
    }
    __syncthreads();
    #pragma unroll
    for (int kk = 0; kk < 2; ++kk) {
      bf16x8 aF[4], bF[4];
      #pragma unroll
      for (int i = 0; i < 4; ++i) {
        const int rowa = wm * 64 + i * 16 + l15;
        const int cha = (kk * 4 + g) ^ (rowa & 7);
        aF[i] = *(const bf16x8*)((const char*)As + rowa * 128 + cha * 16);
        const int rowb = wn * 64 + i * 16 + l15;
        const int chb = (kk * 4 + g) ^ (rowb & 7);
        bF[i] = *(const bf16x8*)((const char*)Bs + rowb * 128 + chb * 16);
      }
      #pragma unroll
      for (int i = 0; i < 4; ++i)
        #pragma unroll
        for (int j = 0; j < 4; ++j)
          acc[i][j] = mfma16(aF[i], bF[j], acc[i][j]);
    }
    __syncthreads();
  }

  // epilogue: S[row][col] = bf16(exp(acc))   (m = 0 softmax, validated R6/R7)
  __bf16* Srow = S + (size_t)batch * 2048 * 2048;
  #pragma unroll
  for (int i = 0; i < 4; ++i) {
    #pragma unroll
    for (int r = 0; r < 4; ++r) {
      const int mrow = mt * 128 + wm * 64 + i * 16 + g * 4 + r;
      #pragma unroll
      for (int j = 0; j < 4; ++j) {
        const int ncol = nt * 128 + wn * 64 + j * 16 + l15;
        Srow[(size_t)mrow * 2048 + ncol] = (__bf16)__expf(acc[i][j][r]);
      }
    }
  }
}

// ============ kernel 6: out = (S @ vT-rows) / (S @ 1) for a 4-batch group ============
// M=2048 per batch, N=512, K=2048. BM=64 BN=128 BK=64; 4 waves 2x2 (32x64/wave).
// l (row sums) accumulated via ones-MFMA alongside; divide in epilogue.
__global__ __launch_bounds__(256, 2) void k_pv(
    const __bf16* __restrict__ S, const __bf16* __restrict__ vT,
    float* __restrict__ out) {
  __shared__ alignas(16) __bf16 As[4096];    //  64 rows x 64 k
  __shared__ alignas(16) __bf16 Bs[8192];    // 128 rows x 64 k
  const int id = blockIdx.x;
  const int batch = id >> 7, local = id & 127;
  const int nt = local & 3, mt = local >> 2;   // mt 0..31, nt 0..3
  const int tid = threadIdx.x, w = tid >> 6, lane = tid & 63;
  const int g = lane >> 4, l15 = lane & 15;
  const int wm = w >> 1, wn = w & 1;
  f32x4 acc[2][4] = {};
  f32x4 l_acc[2] = {};
  bf16x8 ones;
  #pragma unroll
  for (int j = 0; j < 8; ++j) ones[j] = (__bf16)1.0f;

  const char* Ab = (const char*)(S  + ((size_t)batch * 2048 + mt * 64) * 2048);
  const char* Bb = (const char*)(vT + ((size_t)batch * 512 + nt * 128) * 2048);

  for (int kt = 0; kt < 32; ++kt) {
    const int k0b = kt * 128;
    // stage A: 64 rows x 128B = 8KB -> 2 rounds of 256x16B
    #pragma unroll
    for (int i = 0; i < 2; ++i) {
      const int L = i * 4096 + tid * 16;
      const int row = L >> 7, ch = (L >> 4) & 7, sch = ch ^ (row & 7);
      gload16(Ab + (size_t)row * 4096 + k0b + sch * 16, (char*)As + L);
    }
    // stage B: 128 rows x 128B = 16KB -> 4 rounds
    #pragma unroll
    for (int i = 0; i < 4; ++i) {
      const int L = i * 4096 + tid * 16;
      const int row = L >> 7, ch = (L >> 4) & 7, sch = ch ^ (row & 7);
      gload16(Bb + (size_t)row * 4096 + k0b + sch * 16, (char*)Bs + L);
    }
    __syncthreads();
    #pragma unroll
    for (int kk = 0; kk < 2; ++kk) {
      bf16x8 aF[2], bF[4];
      #pragma unroll
      for (int i = 0; i < 2; ++i) {
        const int rowa = wm * 32 + i * 16 + l15;
        const int cha = (kk * 4 + g) ^ (rowa & 7);
        aF[i] = *(const bf16x8*)((const char*)As + rowa * 128 + cha * 16);
      }
      #pragma unroll
      for (int j = 0; j < 4; ++j) {
        const int rowb = wn * 64 + j * 16 + l15;
        const int chb = (kk * 4 + g) ^ (rowb & 7);
        bF[j] = *(const bf16x8*)((const char*)Bs + rowb * 128 + chb * 16);
      }
      #pragma unroll
      for (int i = 0; i < 2; ++i) {
        #pragma unroll
        for (int j = 0; j < 4; ++j)
          acc[i][j] = mfma16(aF[i], bF[j], acc[i][j]);
        l_acc[i] = mfma16(aF[i], ones, l_acc[i]);
      }
    }
    __syncthreads();
  }

  // epilogue: divide by row-sum l, write f32
  #pragma unroll
  for (int i = 0; i < 2; ++i) {
    #pragma unroll
    for (int r = 0; r < 4; ++r) {
      const size_t mrow = (size_t)batch * 2048 + mt * 64 + wm * 32 + i * 16 + g * 4 + r;
      const float inv = 1.0f / l_acc[i][r];
      #pragma unroll
      for (int j = 0; j < 4; ++j) {
        const int ncol = nt * 128 + wn * 64 + j * 16 + l15;
        out[mrow * 512 + ncol] = acc[i][j][r] * inv;
      }
    }
  }
}

// ============ launcher ============
extern "C" void kernel_launch(void* const* d_in, const int* in_sizes, int n_in,
                              void* d_out, int out_size, void* d_ws, size_t ws_size,
                              hipStream_t stream) {
  const float* tf  = (const float*)d_in[0];
  const float* env = (const float*)d_in[1];
  const float* Wq  = (const float*)d_in[2];
  const float* bq  = (const float*)d_in[3];
  const float* Wk  = (const float*)d_in[4];
  const float* bk  = (const float*)d_in[5];
  const float* Wv  = (const float*)d_in[6];
  const float* bv  = (const float*)d_in[7];
  const float* Wg  = (const float*)d_in[8];
  const float* bg  = (const float*)d_in[9];
  float* out = (float*)d_out;
  char* ws = (char*)d_ws;

  __bf16* xb   = (__bf16*)(ws + XB_OFF);
  __bf16* Sbuf = (__bf16*)(ws + S_OFF);
  __bf16* qb   = (__bf16*)(ws + Q_OFF);
  __bf16* kb   = (__bf16*)(ws + K_OFF);
  __bf16* vb   = (__bf16*)(ws + V_OFF);
  __bf16* vT   = (__bf16*)(ws + VT_OFF);
  __bf16* Wt   = (__bf16*)(ws + WT_OFF);
  float* biasc = (float*)(ws + BIAS_OFF);
  float* gate  = (float*)(ws + GATE_OFF);

  k_xbgate<<<dim3(16384), dim3(256), 0, stream>>>(tf, env, Wg, bg, xb, gate);
  k_wt<<<dim3(1536), dim3(256), 0, stream>>>(Wq, Wk, Wv, bq, bk, bv, Wt, biasc);
  k_gemm<<<dim3(1536), dim3(256), 0, stream>>>(xb, Wt, biasc, gate, qb, kb, vb);
  k_vtr<<<dim3(32, 8, 8), dim3(256), 0, stream>>>(vb, vT);

  // attention as two GEMMs per 4-batch group; S reuses the dead xb region
  const size_t hb = 4UL * 2048 * 512;     // q/k elements per group
  const size_t hv = 4UL * 512 * 2048;     // vT elements per group
  const size_t ho = 4UL * 2048 * 512;     // out elements per group
  k_sexp<<<dim3(1024), dim3(256), 0, stream>>>(qb, kb, Sbuf);
  k_pv  <<<dim3(512),  dim3(256), 0, stream>>>(Sbuf, vT, out);
  k_sexp<<<dim3(1024), dim3(256), 0, stream>>>(qb + hb, kb + hb, Sbuf);
  k_pv  <<<dim3(512),  dim3(256), 0, stream>>>(Sbuf, vT + hv, out + ho);
}